// Round 12
// baseline (309.337 us; speedup 1.0000x reference)
//
#include <hip/hip_runtime.h>
#include <math.h>

#define B_ 2
#define P_ 16384
#define C_ 5
#define S_ 4096
#define KNN_ 8
#define L_ 64

typedef unsigned short u16;
typedef unsigned int u32;

// ---- static scratch: fully rewritten every call before any read ----
__device__ int   g_idxk[B_ * KNN_ * S_];
__device__ float g_partials[1024 * 128];       // per-block BN partial sums (deterministic)

__device__ __forceinline__ float bf2f(u16 u) {
  union { u32 i; float f; } c; c.i = ((u32)u) << 16; return c.f;
}
__device__ __forceinline__ u16 f2bf(float f) {
  union { float f; u32 i; } c; c.f = f;
  u32 r = c.i + 0x7fffu + ((c.i >> 16) & 1u);
  return (u16)(r >> 16);
}
__device__ __forceinline__ float ldany(const void* p, int i, int f32) {
  return f32 ? ((const float*)p)[i] : bf2f(((const u16*)p)[i]);
}

// ---- (d, idx) -> fixed-exponent positive double; order == (d desc, idx asc); unique ----
__device__ __forceinline__ double packkey(float d, int idx) {
  u32 bits = __float_as_uint(d);
  u32 key = bits ^ ((u32)(((int)bits) >> 31) | 0x80000000u);  // monotone u32 map of f32
  int hi = (int)(0x3FF00000u | (key >> 12));
  int lo = (int)((key << 20) | ((u32)(16383 - idx) << 6));
  return __hiloint2double(hi, lo);
}
__device__ __forceinline__ int keyidx(double w) {
  return 16383 - (int)(((u32)__double2loint(w) >> 6) & 16383u);
}
__device__ __forceinline__ void cmpswap(double& a, double& b) {
  double hi = fmax(a, b), lo = fmin(a, b);
  a = hi; b = lo;
}
// acc: sorted desc top-8; k: 8 new keys (unordered). After: acc = sorted desc top-8 of union.
__device__ __forceinline__ void flush8(double* a, double* k) {
  cmpswap(k[0], k[1]); cmpswap(k[2], k[3]); cmpswap(k[4], k[5]); cmpswap(k[6], k[7]);
  cmpswap(k[0], k[2]); cmpswap(k[1], k[3]); cmpswap(k[4], k[6]); cmpswap(k[5], k[7]);
  cmpswap(k[1], k[2]); cmpswap(k[5], k[6]);
  cmpswap(k[0], k[4]); cmpswap(k[1], k[5]); cmpswap(k[2], k[6]); cmpswap(k[3], k[7]);
  cmpswap(k[2], k[4]); cmpswap(k[3], k[5]);
  cmpswap(k[1], k[2]); cmpswap(k[3], k[4]); cmpswap(k[5], k[6]);
  a[0] = fmax(a[0], k[7]); a[1] = fmax(a[1], k[6]);
  a[2] = fmax(a[2], k[5]); a[3] = fmax(a[3], k[4]);
  a[4] = fmax(a[4], k[3]); a[5] = fmax(a[5], k[2]);
  a[6] = fmax(a[6], k[1]); a[7] = fmax(a[7], k[0]);
  cmpswap(a[0], a[4]); cmpswap(a[1], a[5]); cmpswap(a[2], a[6]); cmpswap(a[3], a[7]);
  cmpswap(a[0], a[2]); cmpswap(a[1], a[3]); cmpswap(a[4], a[6]); cmpswap(a[5], a[7]);
  cmpswap(a[0], a[1]); cmpswap(a[2], a[3]); cmpswap(a[4], a[5]); cmpswap(a[6], a[7]);
}

__device__ __forceinline__ int chk_bad(const void* p, int n, int tid) {
  int bad = 0;
  for (int i = tid; i < n; i += 256) {
    float f = bf2f(((const u16*)p)[i]);
    if (!(f == f) || fabsf(f) > 1024.0f) bad = 1;
  }
  return bad;
}

// ---------------- fused kNN + BN-partials ----------------
// 1024 blocks x 256 thr; 8 queries/block; 64 lanes/query; 2 q/thread.
// Double-buffered 16 KB LDS chunks (one barrier per chunk).
__global__ __launch_bounds__(256, 4) void k_knn(const void* __restrict__ xv,
                                                const void* __restrict__ Wpos,
                                                const void* __restrict__ bpos,
                                                const void* __restrict__ Wconv,
                                                const void* __restrict__ bconv) {
  __shared__ float4 s4[2][1024];            // 32 KB double buffer
  __shared__ float sWpos[320], sbpos[32], sWconv[128], sbconv[32];
  __shared__ float sacc[4][128];
  __shared__ int sidx[8];
  __shared__ int sp0[8];
  __shared__ int sbad, sbw;
  __shared__ float sred[16];
  int tid = threadIdx.x;
  int l = tid & 63, g = tid >> 6;           // 4 wave-groups, 2 queries each
  int sg0 = blockIdx.x * 8 + g * 2;
  int b = sg0 >> 12;
  int base0 = b * C_ * P_, base1 = base0 + P_, base2 = base1 + P_;

  // dtype detect (per block; same data/criterion -> uniform across blocks)
  if (tid == 0) { sbad = 0; sbw = 0; }
  __syncthreads();
  if (chk_bad(xv, 1024, tid)) atomicOr(&sbad, 1);
  if (chk_bad(Wpos, 320, tid) | chk_bad(Wconv, 128, tid)) atomicOr(&sbw, 1);
  __syncthreads();
  const int f32 = sbad, wf32 = sbw;

  // stage weights (used in the BN tail)
  for (int i2 = tid; i2 < 320; i2 += 256) sWpos[i2] = ldany(Wpos, i2, wf32);
  if (tid < 128) sWconv[tid] = ldany(Wconv, tid, wf32);
  if (tid < 32) { sbpos[tid] = ldany(bpos, tid, wf32); sbconv[tid] = ldany(bconv, tid, wf32); }

  // min/max of channels 0,1 (exact; order-independent)
  float mn0 = INFINITY, mx0 = -INFINITY, mn1 = INFINITY, mx1 = -INFINITY;
  for (int p = tid; p < P_; p += 256) {
    float v0 = ldany(xv, base0 + p, f32);
    float v1 = ldany(xv, base1 + p, f32);
    mn0 = fminf(mn0, v0); mx0 = fmaxf(mx0, v0);
    mn1 = fminf(mn1, v1); mx1 = fmaxf(mx1, v1);
  }
  for (int off = 32; off; off >>= 1) {
    mn0 = fminf(mn0, __shfl_down(mn0, off)); mx0 = fmaxf(mx0, __shfl_down(mx0, off));
    mn1 = fminf(mn1, __shfl_down(mn1, off)); mx1 = fmaxf(mx1, __shfl_down(mx1, off));
  }
  if (l == 0) {
    sred[g * 4 + 0] = mn0; sred[g * 4 + 1] = mx0;
    sred[g * 4 + 2] = mn1; sred[g * 4 + 3] = mx1;
  }
  __syncthreads();
  mn0 = fminf(fminf(sred[0], sred[4]), fminf(sred[8], sred[12]));
  mx0 = fmaxf(fmaxf(sred[1], sred[5]), fmaxf(sred[9], sred[13]));
  mn1 = fminf(fminf(sred[2], sred[6]), fminf(sred[10], sred[14]));
  mx1 = fmaxf(fmaxf(sred[3], sred[7]), fmaxf(sred[11], sred[15]));

  // ---- phase A: nearest candidate (2D) for the 2 grid queries ----
  float ps0[2], ps1[2], xx2[2], best[2]; int bestp[2];
#pragma unroll
  for (int qq = 0; qq < 2; ++qq) {
    int s = (sg0 + qq) & (S_ - 1);
    float mm0 = (float)(s & (L_ - 1)) * 0.015625f;
    float mm1 = (float)(s >> 6) * 0.015625f;
    ps0[qq] = __fadd_rn(__fmul_rn(mm0, __fsub_rn(mx0, mn0)), mn0);
    ps1[qq] = __fadd_rn(__fmul_rn(mm1, __fsub_rn(mx1, mn1)), mn1);
    xx2[qq] = __fadd_rn(__fmul_rn(ps0[qq], ps0[qq]), __fmul_rn(ps1[qq], ps1[qq]));
    best[qq] = -INFINITY; bestp[qq] = 0x7fffffff;
  }
  // prologue: stage chunk 0
  {
#pragma unroll
    for (int r = 0; r < 4; ++r) {
      int i = r * 256 + tid;
      float a0 = ldany(xv, base0 + i, f32);
      float a1 = ldany(xv, base1 + i, f32);
      float xx = __fadd_rn(__fmul_rn(a0, a0), __fmul_rn(a1, a1));
      s4[0][i] = make_float4(a0, a1, xx, 0.0f);
    }
  }
  __syncthreads();
  for (int c = 0; c < 16; ++c) {
    float a0r[4], a1r[4];
    if (c < 15) {
#pragma unroll
      for (int r = 0; r < 4; ++r) {
        int gi = (c + 1) * 1024 + r * 256 + tid;
        a0r[r] = ldany(xv, base0 + gi, f32);
        a1r[r] = ldany(xv, base1 + gi, f32);
      }
    }
    const float4* cb = s4[c & 1];
    for (int t = 0; t < 16; ++t) {
      float4 v = cb[t * 64 + l];
      int ix = c * 1024 + t * 64 + l;       // strictly increasing in-thread
#pragma unroll
      for (int qq = 0; qq < 2; ++qq) {
        float dot = __fadd_rn(__fmul_rn(v.x, ps0[qq]), __fmul_rn(v.y, ps1[qq]));
        float inner = __fmul_rn(-2.0f, dot);
        float d = __fsub_rn(__fsub_rn(-v.z, inner), xx2[qq]);
        bool gt = d > best[qq];             // strict > keeps lowest idx on in-thread ties
        best[qq] = gt ? d : best[qq];
        bestp[qq] = gt ? ix : bestp[qq];
      }
    }
    if (c < 15) {
      float4* nb = s4[(c + 1) & 1];
#pragma unroll
      for (int r = 0; r < 4; ++r) {
        float xx = __fadd_rn(__fmul_rn(a0r[r], a0r[r]), __fmul_rn(a1r[r], a1r[r]));
        nb[r * 256 + tid] = make_float4(a0r[r], a1r[r], xx, 0.0f);
      }
    }
    __syncthreads();
  }
#pragma unroll
  for (int qq = 0; qq < 2; ++qq) {
    float v = best[qq]; int ix = bestp[qq];
    for (int m = 1; m < 64; m <<= 1) {
      float ov = __shfl_xor(v, m, 64); int op = __shfl_xor(ix, m, 64);
      if (ov > v || (ov == v && op < ix)) { v = ov; ix = op; }
    }
    if (l == 0) sidx[g * 2 + qq] = ix;
  }
  __syncthreads();

  // ---- phase B: top-8 (3D) for the 2 sampled queries ----
  float q0[2], q1[2], q2[2], xx3q[2];
  double acc[2][8], kb[2][8];
#pragma unroll
  for (int qq = 0; qq < 2; ++qq) {
    int qi = sidx[g * 2 + qq] & (P_ - 1);
    q0[qq] = ldany(xv, base0 + qi, f32);
    q1[qq] = ldany(xv, base1 + qi, f32);
    q2[qq] = ldany(xv, base2 + qi, f32);
    xx3q[qq] = __fadd_rn(__fadd_rn(__fmul_rn(q0[qq], q0[qq]), __fmul_rn(q1[qq], q1[qq])),
                         __fmul_rn(q2[qq], q2[qq]));
#pragma unroll
    for (int k = 0; k < 8; ++k) acc[qq][k] = -1.0;   // below all keys (keys in [1,2))
  }
  {
#pragma unroll
    for (int r = 0; r < 4; ++r) {
      int i = r * 256 + tid;
      float a0 = ldany(xv, base0 + i, f32);
      float a1 = ldany(xv, base1 + i, f32);
      float a2 = ldany(xv, base2 + i, f32);
      float xx = __fadd_rn(__fadd_rn(__fmul_rn(a0, a0), __fmul_rn(a1, a1)), __fmul_rn(a2, a2));
      s4[0][i] = make_float4(a0, a1, a2, xx);
    }
  }
  __syncthreads();
  for (int c = 0; c < 16; ++c) {
    float a0r[4], a1r[4], a2r[4];
    if (c < 15) {
#pragma unroll
      for (int r = 0; r < 4; ++r) {
        int gi = (c + 1) * 1024 + r * 256 + tid;
        a0r[r] = ldany(xv, base0 + gi, f32);
        a1r[r] = ldany(xv, base1 + gi, f32);
        a2r[r] = ldany(xv, base2 + gi, f32);
      }
    }
    const float4* cb = s4[c & 1];
#pragma unroll
    for (int t = 0; t < 16; ++t) {
      float4 v = cb[t * 64 + l];
      int ix = c * 1024 + t * 64 + l;
#pragma unroll
      for (int qq = 0; qq < 2; ++qq) {
        float dot = __fadd_rn(__fadd_rn(__fmul_rn(v.x, q0[qq]), __fmul_rn(v.y, q1[qq])),
                              __fmul_rn(v.z, q2[qq]));
        float inner = __fmul_rn(-2.0f, dot);
        float d = __fsub_rn(__fsub_rn(-v.w, inner), xx3q[qq]);
        kb[qq][t & 7] = packkey(d, ix);
      }
      if ((t & 7) == 7) {                   // batch flush: exact top-8 union
        flush8(acc[0], kb[0]);
        flush8(acc[1], kb[1]);
      }
    }
    if (c < 15) {
      float4* nb = s4[(c + 1) & 1];
#pragma unroll
      for (int r = 0; r < 4; ++r) {
        float xx = __fadd_rn(__fadd_rn(__fmul_rn(a0r[r], a0r[r]), __fmul_rn(a1r[r], a1r[r])),
                             __fmul_rn(a2r[r], a2r[r]));
        nb[r * 256 + tid] = make_float4(a0r[r], a1r[r], a2r[r], xx);
      }
    }
    __syncthreads();
  }
  // 8 extraction rounds across the 64-lane wave (keys unique -> exact)
  double wk[2] = {0.0, 0.0};
#pragma unroll
  for (int qq = 0; qq < 2; ++qq) {
#pragma unroll
    for (int r = 0; r < 8; ++r) {
      double w = acc[qq][0];
      for (int m = 1; m < 64; m <<= 1) w = fmax(w, __shfl_xor(w, m, 64));
      if (l == r) wk[qq] = w;               // lane r keeps rank r
      bool cns = (acc[qq][0] == w);         // only the winner consumes its head
#pragma unroll
      for (int k = 0; k < 7; ++k) acc[qq][k] = cns ? acc[qq][k + 1] : acc[qq][k];
      acc[qq][7] = cns ? -1.0 : acc[qq][7];
    }
  }
  if (l < 8) {
#pragma unroll
    for (int qq = 0; qq < 2; ++qq) {
      int s = (sg0 + qq) & (S_ - 1);
      g_idxk[b * 32768 + l * 4096 + s] = keyidx(wk[qq]);   // rank-major (B,k,s)
    }
  }

  // ---- tail: BN partial sums for this block's 64 elements ----
  // Scramble algebra: element n=i*8+j uses p = idxk[r][s], p0 = idxk[r][s&~7]
  // with r = n>>12, s = n&4095. This block owns queries base..base+7 (base = blk*8,
  // 8-aligned) for ALL ranks r -> its 64 elements pair (rank r of query s) with
  // (rank r of query base). Publish query-base ranks (wave-group 0's wk[0]).
  if (g == 0 && l < 8) sp0[l] = keyidx(wk[0]) & (P_ - 1);
  __syncthreads();
  // wave-group g: 16 elements, lanes 0..15: rank r = l&7, query qq = l>>3
  double k1s = __shfl(wk[1], l & 7, 16);    // rank (l&7) of query sg0+1
  bool active = (l < 16);
  double myk = (l < 8) ? wk[0] : k1s;
  int p = keyidx(myk) & (P_ - 1);
  int p0 = sp0[l & 7];
  float xvv[4] = {0, 0, 0, 0}, pc3[3] = {0, 0, 0};
  if (active) {
#pragma unroll
    for (int cc = 0; cc < 4; ++cc) xvv[cc] = ldany(xv, base0 + cc * P_ + p, f32);
#pragma unroll
    for (int cc = 0; cc < 3; ++cc) pc3[cc] = ldany(xv, base0 + cc * P_ + p0, f32);
  }
  float d0 = xvv[0] - pc3[0], d1 = xvv[1] - pc3[1], d2 = xvv[2] - pc3[2];
  float sq = d0 * d0 + d1 * d1 + d2 * d2;
  float temp = (sq > 0.0f) ? sqrtf(sq) : 0.0f;
  float pe[10] = {xvv[0], xvv[1], xvv[2], pc3[0], pc3[1], pc3[2], d0, d1, d2, temp};
#pragma unroll
  for (int o = 0; o < 64; ++o) {
    float v;
    if (o < 32) {                           // conv branch
      v = sbconv[o];
#pragma unroll
      for (int cc = 0; cc < 4; ++cc) v = fmaf(sWconv[o * 4 + cc], xvv[cc], v);
    } else {                                // pos branch
      v = sbpos[o - 32];
#pragma unroll
      for (int cc = 0; cc < 10; ++cc) v = fmaf(sWpos[(o - 32) * 10 + cc], pe[cc], v);
    }
    v = active ? v : 0.0f;
    float s = v, q = v * v;
    for (int m = 1; m < 16; m <<= 1) { s += __shfl_xor(s, m, 16); q += __shfl_xor(q, m, 16); }
    if (l == 0) { sacc[g][o * 2] = s; sacc[g][o * 2 + 1] = q; }
  }
  __syncthreads();
  if (tid < 128) {
    g_partials[blockIdx.x * 128 + tid] =
        sacc[0][tid] + sacc[1][tid] + sacc[2][tid] + sacc[3][tid];
  }
}

// ---------------- pass 2 : BN stats from partials + recompute + attention + output ----------------
__global__ __launch_bounds__(256) void k_pass2(const void* __restrict__ x,
                                               const void* __restrict__ Wpos,
                                               const void* __restrict__ bpos,
                                               const void* __restrict__ Wconv,
                                               const void* __restrict__ bconv,
                                               const void* __restrict__ g1,
                                               const void* __restrict__ be1,
                                               const void* __restrict__ g2,
                                               const void* __restrict__ be2,
                                               const void* __restrict__ Wa1,
                                               const void* __restrict__ ba1,
                                               const void* __restrict__ Wa2,
                                               const void* __restrict__ ba2,
                                               const void* __restrict__ Wb1,
                                               const void* __restrict__ bb1,
                                               const void* __restrict__ Wb2,
                                               const void* __restrict__ bb2,
                                               void* __restrict__ out) {
  __shared__ float sWpos[320], sbpos[32], sWconv[128], sbconv[32];
  __shared__ float sWa1[2048], sba1[32], sWa2[32];
  __shared__ float sWb1[64 * 65];
  __shared__ float sbb1[64], sWb2[256], sbb2[64], sstats[128];
  __shared__ float sp2[2][128];
  __shared__ float sba2;
  __shared__ int sbx, sbw;
  int tid = threadIdx.x;
  if (tid == 0) { sbx = 0; sbw = 0; }
  __syncthreads();
  if (chk_bad(x, 1024, tid)) atomicOr(&sbx, 1);
  if (chk_bad(Wa1, 2048, tid) | chk_bad(Wb1, 4096, tid)) atomicOr(&sbw, 1);
  __syncthreads();
  int xf32 = sbx, wf32 = sbw;
  // sum block partials (fixed order -> deterministic)
  {
    int slot = tid & 127, half = tid >> 7;
    float a = 0.f;
    for (int blk = half * 512; blk < half * 512 + 512; ++blk)
      a += g_partials[blk * 128 + slot];
    sp2[half][slot] = a;
  }
  for (int i2 = tid; i2 < 320; i2 += 256) sWpos[i2] = ldany(Wpos, i2, wf32);
  if (tid < 128) sWconv[tid] = ldany(Wconv, tid, wf32);
  if (tid < 32) { sbpos[tid] = ldany(bpos, tid, wf32); sbconv[tid] = ldany(bconv, tid, wf32); }
  for (int i2 = tid; i2 < 2048; i2 += 256) sWa1[i2] = ldany(Wa1, i2, wf32);
  for (int i2 = tid; i2 < 4096; i2 += 256) sWb1[(i2 >> 6) * 65 + (i2 & 63)] = ldany(Wb1, i2, wf32);
  if (tid >= 32 && tid < 64) { sba1[tid - 32] = ldany(ba1, tid - 32, wf32); sWa2[tid - 32] = ldany(Wa2, tid - 32, wf32); }
  if (tid >= 64 && tid < 128) { sbb1[tid - 64] = ldany(bb1, tid - 64, wf32); sbb2[tid - 64] = ldany(bb2, tid - 64, wf32); }
  sWb2[tid] = ldany(Wb2, tid, wf32);
  if (tid == 0) sba2 = ldany(ba2, 0, wf32);
  __syncthreads();
  if (tid >= 128 && tid < 192) {            // BN stats
    int ch = tid - 128;
    float sum = sp2[0][ch * 2] + sp2[1][ch * 2];
    float sq = sp2[0][ch * 2 + 1] + sp2[1][ch * 2 + 1];
    float mean = sum * (1.0f / 65536.0f);
    float var = sq * (1.0f / 65536.0f) - mean * mean;
    int o = ch & 31;
    float gg = ldany(ch < 32 ? g1 : g2, o, wf32);
    float be = ldany(ch < 32 ? be1 : be2, o, wf32);
    float scale = gg / sqrtf(var + 1e-5f);
    sstats[ch * 2] = scale;
    sstats[ch * 2 + 1] = be - mean * scale;
  }
  __syncthreads();
  int g = blockIdx.x * 32 + (tid >> 3);     // group = (b,i)
  int j = tid & 7;
  int b = g >> 12, i = g & (S_ - 1);
  int n = i * 8 + j;
  const int* fb = g_idxk + b * 32768;
  int xbase = b * C_ * P_;
  int p = fb[n] & (P_ - 1);
  int p0 = fb[n & ~7] & (P_ - 1);
  float xvv[4];
#pragma unroll
  for (int c = 0; c < 4; ++c) xvv[c] = ldany(x, xbase + c * P_ + p, xf32);
  float pc3[3];
#pragma unroll
  for (int c = 0; c < 3; ++c) pc3[c] = ldany(x, xbase + c * P_ + p0, xf32);
  float d0 = xvv[0] - pc3[0], d1 = xvv[1] - pc3[1], d2 = xvv[2] - pc3[2];
  float sq = d0 * d0 + d1 * d1 + d2 * d2;
  float temp = (sq > 0.0f) ? sqrtf(sq) : 0.0f;
  float pe[10] = {xvv[0], xvv[1], xvv[2], pc3[0], pc3[1], pc3[2], d0, d1, d2, temp};
  float feat[64];
#pragma unroll
  for (int o = 0; o < 32; ++o) {
    float acc = sbconv[o];
#pragma unroll
    for (int c = 0; c < 4; ++c) acc = fmaf(sWconv[o * 4 + c], xvv[c], acc);
    feat[o] = acc;
  }
#pragma unroll
  for (int o = 0; o < 32; ++o) {
    float acc = sbpos[o];
#pragma unroll
    for (int c = 0; c < 10; ++c) acc = fmaf(sWpos[o * 10 + c], pe[c], acc);
    feat[32 + o] = acc;
  }
#pragma unroll
  for (int c = 0; c < 64; ++c) {
    float v = fmaf(feat[c], sstats[c * 2], sstats[c * 2 + 1]);
    feat[c] = (v >= 0.f) ? v : 0.2f * v;
  }
  float att = sba2;
  for (int h = 0; h < 32; ++h) {
    float acc = sba1[h];
#pragma unroll
    for (int c = 0; c < 64; ++c) acc = fmaf(sWa1[h * 64 + c], feat[c], acc);
    acc = (acc >= 0.f) ? acc : 0.2f * acc;
    att = fmaf(sWa2[h], acc, att);
  }
  float mxv = att;
  for (int mk = 1; mk < 8; mk <<= 1) mxv = fmaxf(mxv, __shfl_xor(mxv, mk, 8));
  float e = expf(att - mxv);
  float se = e;
  for (int mk = 1; mk < 8; mk <<= 1) se += __shfl_xor(se, mk, 8);
  float a = e / se;
#pragma unroll
  for (int c = 0; c < 64; ++c) {
    float w = feat[c] * a;
    w += __shfl_xor(w, 1, 8);
    w += __shfl_xor(w, 2, 8);
    w += __shfl_xor(w, 4, 8);
    feat[c] = w;
  }
  float xc0 = ldany(x, xbase + p0, xf32);
  float xc1 = ldany(x, xbase + P_ + p0, xf32);
  float xc2 = ldany(x, xbase + 2 * P_ + p0, xf32);
  float xc3 = ldany(x, xbase + 3 * P_ + p0, xf32);
  int obase = b * 69 * S_;
#pragma unroll
  for (int oc = 0; oc < 8; ++oc) {
    int o = j * 8 + oc;
    float acc = sbb1[o];
#pragma unroll
    for (int c = 0; c < 64; ++c) acc = fmaf(sWb1[o * 65 + c], feat[c], acc);
    float acc2 = sbb2[o];
    acc2 = fmaf(sWb2[o * 4 + 0], xc0, acc2);
    acc2 = fmaf(sWb2[o * 4 + 1], xc1, acc2);
    acc2 = fmaf(sWb2[o * 4 + 2], xc2, acc2);
    acc2 = fmaf(sWb2[o * 4 + 3], xc3, acc2);
    float r = acc + acc2;
    r = (r >= 0.f) ? r : 0.01f * r;
    int oi = obase + (5 + o) * S_ + i;
    if (xf32) ((float*)out)[oi] = r; else ((u16*)out)[oi] = f2bf(r);
  }
  if (j == 0) {                              // raw pass-through of x1[:, :5, :, 0]
#pragma unroll
    for (int c = 0; c < 5; ++c) {
      int oi = obase + c * S_ + i;
      if (xf32) ((float*)out)[oi] = ((const float*)x)[xbase + c * P_ + p0];
      else      ((u16*)out)[oi]   = ((const u16*)x)[xbase + c * P_ + p0];
    }
  }
}

extern "C" void kernel_launch(void* const* d_in, const int* in_sizes, int n_in,
                              void* d_out, int out_size, void* d_ws, size_t ws_size,
                              hipStream_t stream) {
  const void* x     = d_in[0];
  const void* Wpos  = d_in[1];
  const void* bpos  = d_in[2];
  const void* g2    = d_in[3];
  const void* be2   = d_in[4];
  const void* Wconv = d_in[5];
  const void* bconv = d_in[6];
  const void* g1    = d_in[7];
  const void* be1   = d_in[8];
  const void* Wa1   = d_in[9];
  const void* ba1   = d_in[10];
  const void* Wa2   = d_in[11];
  const void* ba2   = d_in[12];
  const void* Wb1   = d_in[13];
  const void* bb1   = d_in[14];
  const void* Wb2   = d_in[15];
  const void* bb2   = d_in[16];
  (void)d_ws; (void)ws_size; (void)in_sizes; (void)n_in;

  hipLaunchKernelGGL(k_knn, dim3(1024), dim3(256), 0, stream, x,
                     Wpos, bpos, Wconv, bconv);
  hipLaunchKernelGGL(k_pass2, dim3(256), dim3(256), 0, stream, x,
                     Wpos, bpos, Wconv, bconv, g1, be1, g2, be2,
                     Wa1, ba1, Wa2, ba2, Wb1, bb1, Wb2, bb2, d_out);
}

// Round 13
// 293.004 us; speedup vs baseline: 1.0557x; 1.0557x over previous
//
#include <hip/hip_runtime.h>
#include <math.h>

#define B_ 2
#define P_ 16384
#define C_ 5
#define S_ 4096
#define KNN_ 8
#define L_ 64

typedef unsigned short u16;
typedef unsigned int u32;

// ---- static scratch: fully rewritten every call before any read ----
__device__ int   g_idxk[B_ * KNN_ * S_];
__device__ float g_partials[1024 * 128];       // per-block BN partial sums (deterministic)

__device__ __forceinline__ float bf2f(u16 u) {
  union { u32 i; float f; } c; c.i = ((u32)u) << 16; return c.f;
}
__device__ __forceinline__ u16 f2bf(float f) {
  union { float f; u32 i; } c; c.f = f;
  u32 r = c.i + 0x7fffu + ((c.i >> 16) & 1u);
  return (u16)(r >> 16);
}
__device__ __forceinline__ float ldany(const void* p, int i, int f32) {
  return f32 ? ((const float*)p)[i] : bf2f(((const u16*)p)[i]);
}

// ---- (d, idx) -> fixed-exponent positive double; order == (d desc, idx asc); unique ----
__device__ __forceinline__ double packkey(float d, int idx) {
  u32 bits = __float_as_uint(d);
  u32 key = bits ^ ((u32)(((int)bits) >> 31) | 0x80000000u);  // monotone u32 map of f32
  int hi = (int)(0x3FF00000u | (key >> 12));
  int lo = (int)((key << 20) | ((u32)(16383 - idx) << 6));
  return __hiloint2double(hi, lo);
}
__device__ __forceinline__ int keyidx(double w) {
  return 16383 - (int)(((u32)__double2loint(w) >> 6) & 16383u);
}
__device__ __forceinline__ void cmpswap(double& a, double& b) {
  double hi = fmax(a, b), lo = fmin(a, b);
  a = hi; b = lo;
}
// acc: sorted desc top-8; k: 8 new keys (unordered). After: acc = sorted desc top-8 of union.
__device__ __forceinline__ void flush8(double* a, double* k) {
  cmpswap(k[0], k[1]); cmpswap(k[2], k[3]); cmpswap(k[4], k[5]); cmpswap(k[6], k[7]);
  cmpswap(k[0], k[2]); cmpswap(k[1], k[3]); cmpswap(k[4], k[6]); cmpswap(k[5], k[7]);
  cmpswap(k[1], k[2]); cmpswap(k[5], k[6]);
  cmpswap(k[0], k[4]); cmpswap(k[1], k[5]); cmpswap(k[2], k[6]); cmpswap(k[3], k[7]);
  cmpswap(k[2], k[4]); cmpswap(k[3], k[5]);
  cmpswap(k[1], k[2]); cmpswap(k[3], k[4]); cmpswap(k[5], k[6]);
  a[0] = fmax(a[0], k[7]); a[1] = fmax(a[1], k[6]);
  a[2] = fmax(a[2], k[5]); a[3] = fmax(a[3], k[4]);
  a[4] = fmax(a[4], k[3]); a[5] = fmax(a[5], k[2]);
  a[6] = fmax(a[6], k[1]); a[7] = fmax(a[7], k[0]);
  cmpswap(a[0], a[4]); cmpswap(a[1], a[5]); cmpswap(a[2], a[6]); cmpswap(a[3], a[7]);
  cmpswap(a[0], a[2]); cmpswap(a[1], a[3]); cmpswap(a[4], a[6]); cmpswap(a[5], a[7]);
  cmpswap(a[0], a[1]); cmpswap(a[2], a[3]); cmpswap(a[4], a[5]); cmpswap(a[6], a[7]);
}

__device__ __forceinline__ int chk_bad(const void* p, int n, int tid) {
  int bad = 0;
  for (int i = tid; i < n; i += 256) {
    float f = bf2f(((const u16*)p)[i]);
    if (!(f == f) || fabsf(f) > 1024.0f) bad = 1;
  }
  return bad;
}

// ---------------- fused kNN + BN-partials ----------------
// 1024 blocks x 256 thr; 8 queries/block; 64 lanes/query; 2 q/thread.
// Single-buffer 16 KB LDS chunks (R10 staging; dbuf spilled — R12 post-mortem).
__global__ __launch_bounds__(256, 4) void k_knn(const void* __restrict__ xv,
                                                const void* __restrict__ Wpos,
                                                const void* __restrict__ bpos,
                                                const void* __restrict__ Wconv,
                                                const void* __restrict__ bconv) {
  __shared__ float4 s4[1024];               // 16 KB
  __shared__ float sWpos[320], sbpos[32], sWconv[128], sbconv[32];
  __shared__ float sacc[4][128];
  __shared__ int sidx[8];
  __shared__ int sp0[8];
  __shared__ int sbad, sbw;
  __shared__ float sred[16];
  int tid = threadIdx.x;
  int l = tid & 63, g = tid >> 6;           // 4 wave-groups, 2 queries each
  int sg0 = blockIdx.x * 8 + g * 2;
  int b = sg0 >> 12;
  int base0 = b * C_ * P_, base1 = base0 + P_, base2 = base1 + P_;

  // dtype detect (per block; same data/criterion -> uniform across blocks)
  if (tid == 0) { sbad = 0; sbw = 0; }
  __syncthreads();
  if (chk_bad(xv, 1024, tid)) atomicOr(&sbad, 1);
  if (chk_bad(Wpos, 320, tid) | chk_bad(Wconv, 128, tid)) atomicOr(&sbw, 1);
  __syncthreads();
  const int f32 = sbad, wf32 = sbw;

  // stage weights (used in the BN tail)
  for (int i2 = tid; i2 < 320; i2 += 256) sWpos[i2] = ldany(Wpos, i2, wf32);
  if (tid < 128) sWconv[tid] = ldany(Wconv, tid, wf32);
  if (tid < 32) { sbpos[tid] = ldany(bpos, tid, wf32); sbconv[tid] = ldany(bconv, tid, wf32); }

  // min/max of channels 0,1 (exact; order-independent)
  float mn0 = INFINITY, mx0 = -INFINITY, mn1 = INFINITY, mx1 = -INFINITY;
  for (int p = tid; p < P_; p += 256) {
    float v0 = ldany(xv, base0 + p, f32);
    float v1 = ldany(xv, base1 + p, f32);
    mn0 = fminf(mn0, v0); mx0 = fmaxf(mx0, v0);
    mn1 = fminf(mn1, v1); mx1 = fmaxf(mx1, v1);
  }
  for (int off = 32; off; off >>= 1) {
    mn0 = fminf(mn0, __shfl_down(mn0, off)); mx0 = fmaxf(mx0, __shfl_down(mx0, off));
    mn1 = fminf(mn1, __shfl_down(mn1, off)); mx1 = fmaxf(mx1, __shfl_down(mx1, off));
  }
  if (l == 0) {
    sred[g * 4 + 0] = mn0; sred[g * 4 + 1] = mx0;
    sred[g * 4 + 2] = mn1; sred[g * 4 + 3] = mx1;
  }
  __syncthreads();
  mn0 = fminf(fminf(sred[0], sred[4]), fminf(sred[8], sred[12]));
  mx0 = fmaxf(fmaxf(sred[1], sred[5]), fmaxf(sred[9], sred[13]));
  mn1 = fminf(fminf(sred[2], sred[6]), fminf(sred[10], sred[14]));
  mx1 = fmaxf(fmaxf(sred[3], sred[7]), fmaxf(sred[11], sred[15]));

  // ---- phase A: nearest candidate (2D) for the 2 grid queries ----
  float ps0[2], ps1[2], xx2[2], best[2]; int bestp[2];
#pragma unroll
  for (int qq = 0; qq < 2; ++qq) {
    int s = (sg0 + qq) & (S_ - 1);
    float mm0 = (float)(s & (L_ - 1)) * 0.015625f;
    float mm1 = (float)(s >> 6) * 0.015625f;
    ps0[qq] = __fadd_rn(__fmul_rn(mm0, __fsub_rn(mx0, mn0)), mn0);
    ps1[qq] = __fadd_rn(__fmul_rn(mm1, __fsub_rn(mx1, mn1)), mn1);
    xx2[qq] = __fadd_rn(__fmul_rn(ps0[qq], ps0[qq]), __fmul_rn(ps1[qq], ps1[qq]));
    best[qq] = -INFINITY; bestp[qq] = 0x7fffffff;
  }
  for (int c = 0; c < 16; ++c) {
    __syncthreads();
#pragma unroll
    for (int r = 0; r < 4; ++r) {
      int i = r * 256 + tid;
      int gi = c * 1024 + i;
      float a0 = ldany(xv, base0 + gi, f32);
      float a1 = ldany(xv, base1 + gi, f32);
      float xx = __fadd_rn(__fmul_rn(a0, a0), __fmul_rn(a1, a1));
      s4[i] = make_float4(a0, a1, xx, 0.0f);
    }
    __syncthreads();
    for (int t = 0; t < 16; ++t) {
      float4 v = s4[t * 64 + l];
      int ix = c * 1024 + t * 64 + l;       // strictly increasing in-thread
#pragma unroll
      for (int qq = 0; qq < 2; ++qq) {
        float dot = __fadd_rn(__fmul_rn(v.x, ps0[qq]), __fmul_rn(v.y, ps1[qq]));
        float inner = __fmul_rn(-2.0f, dot);
        float d = __fsub_rn(__fsub_rn(-v.z, inner), xx2[qq]);
        bool gt = d > best[qq];             // strict > keeps lowest idx on in-thread ties
        best[qq] = gt ? d : best[qq];
        bestp[qq] = gt ? ix : bestp[qq];
      }
    }
  }
#pragma unroll
  for (int qq = 0; qq < 2; ++qq) {
    float v = best[qq]; int ix = bestp[qq];
    for (int m = 1; m < 64; m <<= 1) {
      float ov = __shfl_xor(v, m, 64); int op = __shfl_xor(ix, m, 64);
      if (ov > v || (ov == v && op < ix)) { v = ov; ix = op; }
    }
    if (l == 0) sidx[g * 2 + qq] = ix;
  }
  __syncthreads();

  // ---- phase B: top-8 (3D) for the 2 sampled queries ----
  float q0[2], q1[2], q2[2], xx3q[2];
  double acc[2][8], kb[2][8];
#pragma unroll
  for (int qq = 0; qq < 2; ++qq) {
    int qi = sidx[g * 2 + qq] & (P_ - 1);
    q0[qq] = ldany(xv, base0 + qi, f32);
    q1[qq] = ldany(xv, base1 + qi, f32);
    q2[qq] = ldany(xv, base2 + qi, f32);
    xx3q[qq] = __fadd_rn(__fadd_rn(__fmul_rn(q0[qq], q0[qq]), __fmul_rn(q1[qq], q1[qq])),
                         __fmul_rn(q2[qq], q2[qq]));
#pragma unroll
    for (int k = 0; k < 8; ++k) acc[qq][k] = -1.0;   // below all keys (keys in [1,2))
  }
  for (int c = 0; c < 16; ++c) {
    __syncthreads();
#pragma unroll
    for (int r = 0; r < 4; ++r) {
      int i = r * 256 + tid;
      int gi = c * 1024 + i;
      float a0 = ldany(xv, base0 + gi, f32);
      float a1 = ldany(xv, base1 + gi, f32);
      float a2 = ldany(xv, base2 + gi, f32);
      float xx = __fadd_rn(__fadd_rn(__fmul_rn(a0, a0), __fmul_rn(a1, a1)), __fmul_rn(a2, a2));
      s4[i] = make_float4(a0, a1, a2, xx);
    }
    __syncthreads();
#pragma unroll
    for (int t = 0; t < 16; ++t) {
      float4 v = s4[t * 64 + l];
      int ix = c * 1024 + t * 64 + l;
#pragma unroll
      for (int qq = 0; qq < 2; ++qq) {
        float dot = __fadd_rn(__fadd_rn(__fmul_rn(v.x, q0[qq]), __fmul_rn(v.y, q1[qq])),
                              __fmul_rn(v.z, q2[qq]));
        float inner = __fmul_rn(-2.0f, dot);
        float d = __fsub_rn(__fsub_rn(-v.w, inner), xx3q[qq]);
        kb[qq][t & 7] = packkey(d, ix);
      }
      if ((t & 7) == 7) {                   // batch flush: exact top-8 union
        flush8(acc[0], kb[0]);
        flush8(acc[1], kb[1]);
      }
    }
  }
  // 8 extraction rounds across the 64-lane wave (keys unique -> exact)
  double wk[2] = {0.0, 0.0};
#pragma unroll
  for (int qq = 0; qq < 2; ++qq) {
#pragma unroll
    for (int r = 0; r < 8; ++r) {
      double w = acc[qq][0];
      for (int m = 1; m < 64; m <<= 1) w = fmax(w, __shfl_xor(w, m, 64));
      if (l == r) wk[qq] = w;               // lane r keeps rank r
      bool cns = (acc[qq][0] == w);         // only the winner consumes its head
#pragma unroll
      for (int k = 0; k < 7; ++k) acc[qq][k] = cns ? acc[qq][k + 1] : acc[qq][k];
      acc[qq][7] = cns ? -1.0 : acc[qq][7];
    }
  }
  if (l < 8) {
#pragma unroll
    for (int qq = 0; qq < 2; ++qq) {
      int s = (sg0 + qq) & (S_ - 1);
      g_idxk[b * 32768 + l * 4096 + s] = keyidx(wk[qq]);   // rank-major (B,k,s)
    }
  }

  // ---- tail: BN partial sums for this block's 64 elements ----
  // Element n=i*8+j uses p = idxk[r][s], p0 = idxk[r][s&~7] (r=n>>12, s=n&4095).
  // Block owns queries base..base+7 (8-aligned) for ALL ranks -> pairs
  // (rank r of query s) with (rank r of query base). Publish base ranks.
  if (g == 0 && l < 8) sp0[l] = keyidx(wk[0]) & (P_ - 1);
  __syncthreads();
  // wave-group g: 16 elements, lanes 0..15: rank r = l&7, query qq = l>>3
  double k1s = __shfl(wk[1], l & 7, 16);    // rank (l&7) of query sg0+1
  bool active = (l < 16);
  double myk = (l < 8) ? wk[0] : k1s;
  int p = keyidx(myk) & (P_ - 1);
  int p0 = sp0[l & 7];
  float xvv[4] = {0, 0, 0, 0}, pc3[3] = {0, 0, 0};
  if (active) {
#pragma unroll
    for (int cc = 0; cc < 4; ++cc) xvv[cc] = ldany(xv, base0 + cc * P_ + p, f32);
#pragma unroll
    for (int cc = 0; cc < 3; ++cc) pc3[cc] = ldany(xv, base0 + cc * P_ + p0, f32);
  }
  float d0 = xvv[0] - pc3[0], d1 = xvv[1] - pc3[1], d2 = xvv[2] - pc3[2];
  float sq = d0 * d0 + d1 * d1 + d2 * d2;
  float temp = (sq > 0.0f) ? sqrtf(sq) : 0.0f;
  float pe[10] = {xvv[0], xvv[1], xvv[2], pc3[0], pc3[1], pc3[2], d0, d1, d2, temp};
#pragma unroll
  for (int o = 0; o < 64; ++o) {
    float v;
    if (o < 32) {                           // conv branch
      v = sbconv[o];
#pragma unroll
      for (int cc = 0; cc < 4; ++cc) v = fmaf(sWconv[o * 4 + cc], xvv[cc], v);
    } else {                                // pos branch
      v = sbpos[o - 32];
#pragma unroll
      for (int cc = 0; cc < 10; ++cc) v = fmaf(sWpos[(o - 32) * 10 + cc], pe[cc], v);
    }
    v = active ? v : 0.0f;
    float s = v, q = v * v;
    for (int m = 1; m < 16; m <<= 1) { s += __shfl_xor(s, m, 16); q += __shfl_xor(q, m, 16); }
    if (l == 0) { sacc[g][o * 2] = s; sacc[g][o * 2 + 1] = q; }
  }
  __syncthreads();
  if (tid < 128) {
    g_partials[blockIdx.x * 128 + tid] =
        sacc[0][tid] + sacc[1][tid] + sacc[2][tid] + sacc[3][tid];
  }
}

// ---------------- pass 2 : BN stats from partials + recompute + attention + output ----------------
__global__ __launch_bounds__(256) void k_pass2(const void* __restrict__ x,
                                               const void* __restrict__ Wpos,
                                               const void* __restrict__ bpos,
                                               const void* __restrict__ Wconv,
                                               const void* __restrict__ bconv,
                                               const void* __restrict__ g1,
                                               const void* __restrict__ be1,
                                               const void* __restrict__ g2,
                                               const void* __restrict__ be2,
                                               const void* __restrict__ Wa1,
                                               const void* __restrict__ ba1,
                                               const void* __restrict__ Wa2,
                                               const void* __restrict__ ba2,
                                               const void* __restrict__ Wb1,
                                               const void* __restrict__ bb1,
                                               const void* __restrict__ Wb2,
                                               const void* __restrict__ bb2,
                                               void* __restrict__ out) {
  __shared__ float sWpos[320], sbpos[32], sWconv[128], sbconv[32];
  __shared__ float sWa1[2048], sba1[32], sWa2[32];
  __shared__ float sWb1[64 * 65];
  __shared__ float sbb1[64], sWb2[256], sbb2[64], sstats[128];
  __shared__ float sp2[2][128];
  __shared__ float sba2;
  __shared__ int sbx, sbw;
  int tid = threadIdx.x;
  if (tid == 0) { sbx = 0; sbw = 0; }
  __syncthreads();
  if (chk_bad(x, 1024, tid)) atomicOr(&sbx, 1);
  if (chk_bad(Wa1, 2048, tid) | chk_bad(Wb1, 4096, tid)) atomicOr(&sbw, 1);
  __syncthreads();
  int xf32 = sbx, wf32 = sbw;
  // sum block partials (fixed order -> deterministic)
  {
    int slot = tid & 127, half = tid >> 7;
    float a = 0.f;
    for (int blk = half * 512; blk < half * 512 + 512; ++blk)
      a += g_partials[blk * 128 + slot];
    sp2[half][slot] = a;
  }
  for (int i2 = tid; i2 < 320; i2 += 256) sWpos[i2] = ldany(Wpos, i2, wf32);
  if (tid < 128) sWconv[tid] = ldany(Wconv, tid, wf32);
  if (tid < 32) { sbpos[tid] = ldany(bpos, tid, wf32); sbconv[tid] = ldany(bconv, tid, wf32); }
  for (int i2 = tid; i2 < 2048; i2 += 256) sWa1[i2] = ldany(Wa1, i2, wf32);
  for (int i2 = tid; i2 < 4096; i2 += 256) sWb1[(i2 >> 6) * 65 + (i2 & 63)] = ldany(Wb1, i2, wf32);
  if (tid >= 32 && tid < 64) { sba1[tid - 32] = ldany(ba1, tid - 32, wf32); sWa2[tid - 32] = ldany(Wa2, tid - 32, wf32); }
  if (tid >= 64 && tid < 128) { sbb1[tid - 64] = ldany(bb1, tid - 64, wf32); sbb2[tid - 64] = ldany(bb2, tid - 64, wf32); }
  sWb2[tid] = ldany(Wb2, tid, wf32);
  if (tid == 0) sba2 = ldany(ba2, 0, wf32);
  __syncthreads();
  if (tid >= 128 && tid < 192) {            // BN stats
    int ch = tid - 128;
    float sum = sp2[0][ch * 2] + sp2[1][ch * 2];
    float sq = sp2[0][ch * 2 + 1] + sp2[1][ch * 2 + 1];
    float mean = sum * (1.0f / 65536.0f);
    float var = sq * (1.0f / 65536.0f) - mean * mean;
    int o = ch & 31;
    float gg = ldany(ch < 32 ? g1 : g2, o, wf32);
    float be = ldany(ch < 32 ? be1 : be2, o, wf32);
    float scale = gg / sqrtf(var + 1e-5f);
    sstats[ch * 2] = scale;
    sstats[ch * 2 + 1] = be - mean * scale;
  }
  __syncthreads();
  int g = blockIdx.x * 32 + (tid >> 3);     // group = (b,i)
  int j = tid & 7;
  int b = g >> 12, i = g & (S_ - 1);
  int n = i * 8 + j;
  const int* fb = g_idxk + b * 32768;
  int xbase = b * C_ * P_;
  int p = fb[n] & (P_ - 1);
  int p0 = fb[n & ~7] & (P_ - 1);
  float xvv[4];
#pragma unroll
  for (int c = 0; c < 4; ++c) xvv[c] = ldany(x, xbase + c * P_ + p, xf32);
  float pc3[3];
#pragma unroll
  for (int c = 0; c < 3; ++c) pc3[c] = ldany(x, xbase + c * P_ + p0, xf32);
  float d0 = xvv[0] - pc3[0], d1 = xvv[1] - pc3[1], d2 = xvv[2] - pc3[2];
  float sq = d0 * d0 + d1 * d1 + d2 * d2;
  float temp = (sq > 0.0f) ? sqrtf(sq) : 0.0f;
  float pe[10] = {xvv[0], xvv[1], xvv[2], pc3[0], pc3[1], pc3[2], d0, d1, d2, temp};
  float feat[64];
#pragma unroll
  for (int o = 0; o < 32; ++o) {
    float acc = sbconv[o];
#pragma unroll
    for (int c = 0; c < 4; ++c) acc = fmaf(sWconv[o * 4 + c], xvv[c], acc);
    feat[o] = acc;
  }
#pragma unroll
  for (int o = 0; o < 32; ++o) {
    float acc = sbpos[o];
#pragma unroll
    for (int c = 0; c < 10; ++c) acc = fmaf(sWpos[o * 10 + c], pe[c], acc);
    feat[32 + o] = acc;
  }
#pragma unroll
  for (int c = 0; c < 64; ++c) {
    float v = fmaf(feat[c], sstats[c * 2], sstats[c * 2 + 1]);
    feat[c] = (v >= 0.f) ? v : 0.2f * v;
  }
  float att = sba2;
  for (int h = 0; h < 32; ++h) {
    float acc = sba1[h];
#pragma unroll
    for (int c = 0; c < 64; ++c) acc = fmaf(sWa1[h * 64 + c], feat[c], acc);
    acc = (acc >= 0.f) ? acc : 0.2f * acc;
    att = fmaf(sWa2[h], acc, att);
  }
  float mxv = att;
  for (int mk = 1; mk < 8; mk <<= 1) mxv = fmaxf(mxv, __shfl_xor(mxv, mk, 8));
  float e = expf(att - mxv);
  float se = e;
  for (int mk = 1; mk < 8; mk <<= 1) se += __shfl_xor(se, mk, 8);
  float a = e / se;
#pragma unroll
  for (int c = 0; c < 64; ++c) {
    float w = feat[c] * a;
    w += __shfl_xor(w, 1, 8);
    w += __shfl_xor(w, 2, 8);
    w += __shfl_xor(w, 4, 8);
    feat[c] = w;
  }
  float xc0 = ldany(x, xbase + p0, xf32);
  float xc1 = ldany(x, xbase + P_ + p0, xf32);
  float xc2 = ldany(x, xbase + 2 * P_ + p0, xf32);
  float xc3 = ldany(x, xbase + 3 * P_ + p0, xf32);
  int obase = b * 69 * S_;
#pragma unroll
  for (int oc = 0; oc < 8; ++oc) {
    int o = j * 8 + oc;
    float acc = sbb1[o];
#pragma unroll
    for (int c = 0; c < 64; ++c) acc = fmaf(sWb1[o * 65 + c], feat[c], acc);
    float acc2 = sbb2[o];
    acc2 = fmaf(sWb2[o * 4 + 0], xc0, acc2);
    acc2 = fmaf(sWb2[o * 4 + 1], xc1, acc2);
    acc2 = fmaf(sWb2[o * 4 + 2], xc2, acc2);
    acc2 = fmaf(sWb2[o * 4 + 3], xc3, acc2);
    float r = acc + acc2;
    r = (r >= 0.f) ? r : 0.01f * r;
    int oi = obase + (5 + o) * S_ + i;
    if (xf32) ((float*)out)[oi] = r; else ((u16*)out)[oi] = f2bf(r);
  }
  if (j == 0) {                              // raw pass-through of x1[:, :5, :, 0]
#pragma unroll
    for (int c = 0; c < 5; ++c) {
      int oi = obase + c * S_ + i;
      if (xf32) ((float*)out)[oi] = ((const float*)x)[xbase + c * P_ + p0];
      else      ((u16*)out)[oi]   = ((const u16*)x)[xbase + c * P_ + p0];
    }
  }
}

extern "C" void kernel_launch(void* const* d_in, const int* in_sizes, int n_in,
                              void* d_out, int out_size, void* d_ws, size_t ws_size,
                              hipStream_t stream) {
  const void* x     = d_in[0];
  const void* Wpos  = d_in[1];
  const void* bpos  = d_in[2];
  const void* g2    = d_in[3];
  const void* be2   = d_in[4];
  const void* Wconv = d_in[5];
  const void* bconv = d_in[6];
  const void* g1    = d_in[7];
  const void* be1   = d_in[8];
  const void* Wa1   = d_in[9];
  const void* ba1   = d_in[10];
  const void* Wa2   = d_in[11];
  const void* ba2   = d_in[12];
  const void* Wb1   = d_in[13];
  const void* bb1   = d_in[14];
  const void* Wb2   = d_in[15];
  const void* bb2   = d_in[16];
  (void)d_ws; (void)ws_size; (void)in_sizes; (void)n_in;

  hipLaunchKernelGGL(k_knn, dim3(1024), dim3(256), 0, stream, x,
                     Wpos, bpos, Wconv, bconv);
  hipLaunchKernelGGL(k_pass2, dim3(256), dim3(256), 0, stream, x,
                     Wpos, bpos, Wconv, bconv, g1, be1, g2, be2,
                     Wa1, ba1, Wa2, ba2, Wb1, bb1, Wb2, bb2, d_out);
}